// Round 2
// baseline (579.073 us; speedup 1.0000x reference)
//
#include <hip/hip_runtime.h>

// Shapes (fixed by the reference):
//   B=128, N=48, M=49, E=64, D=256
//   NUMS_BC=[11,11,11]  -> idx offsets {1,12,23}
//   NUMS_SC=[11,11,11,11]-> idx offsets {1,12,23,34}
// All float inputs/outputs are float32; int inputs are int32.

#define DD 256
#define BB 128
#define NN 48
#define MM 49
#define EE 64

typedef unsigned long long u64;

// Wave-level fused (sum, sumsq) reduction across 64 lanes.
__device__ __forceinline__ void wred2(float& s, float& q) {
#pragma unroll
    for (int off = 32; off > 0; off >>= 1) {
        s += __shfl_xor(s, off, 64);
        q += __shfl_xor(q, off, 64);
    }
}

// In-place LayerNorm over D=256 held as 4 values/lane across one wave.
__device__ __forceinline__ void ln4(float& x0, float& x1, float& x2, float& x3,
                                    const float* __restrict__ g,
                                    const float* __restrict__ bb, int d0) {
    float s = x0 + x1 + x2 + x3;
    float q = x0 * x0 + x1 * x1 + x2 * x2 + x3 * x3;
    wred2(s, q);
    float mu  = s * (1.0f / 256.0f);
    float var = q * (1.0f / 256.0f) - mu * mu;
    float rs  = rsqrtf(var + 1e-5f);
    float4 gv = *(const float4*)(g + d0);
    float4 bv = *(const float4*)(bb + d0);
    x0 = (x0 - mu) * rs * gv.x + bv.x;
    x1 = (x1 - mu) * rs * gv.y + bv.y;
    x2 = (x2 - mu) * rs * gv.z + bv.z;
    x3 = (x3 - mu) * rs * gv.w + bv.w;
}

// ---------------------------------------------------------------------------
// Kernel 1: per-batch bond bitmasks. grid=B, block=64 (one wave).
// maskA[b][i] = bitmask over e of (bond_index[b,0,e]+1 == i), i in 1..48.
// ---------------------------------------------------------------------------
__global__ __launch_bounds__(64) void k_masks(const int* __restrict__ bond_index,
                                              u64* __restrict__ maskA,
                                              u64* __restrict__ maskB) {
    const int b = blockIdx.x;
    const int e = threadIdx.x;  // 0..63
    const int bi0 = bond_index[b * 2 * EE + e];
    const int bi1 = bond_index[b * 2 * EE + EE + e];
    for (int i = 0; i < NN; ++i) {
        u64 mA = __ballot(bi0 == i);
        u64 mB = __ballot(bi1 == i);
        if (e == 0) {
            maskA[b * MM + i + 1] = mA;
            maskB[b * MM + i + 1] = mB;
        }
    }
}

// ---------------------------------------------------------------------------
// Kernel 2: bond embeddings hb (f32, ws) and hbrev = hb @ W_rev + b_rev.
// grid = B*4 (16 bonds per block), block = 256 (4 waves; wave w owns bonds
// w*4..w*4+3 in phase 1; phase 2 is a 16x256 @ 256x256 mini-GEMM, hb in LDS).
// ---------------------------------------------------------------------------
__global__ __launch_bounds__(256) void k_bonds(
    const int* __restrict__ bfc, const float* __restrict__ bff,
    const float* __restrict__ bmask,
    const float* __restrict__ table_bc,
    const float* __restrict__ g_bc, const float* __restrict__ be_bc,
    const float* __restrict__ W_bf, const float* __restrict__ b_bf,
    const float* __restrict__ g_bf, const float* __restrict__ be_bf,
    const float* __restrict__ W_rev, const float* __restrict__ b_rev,
    float* __restrict__ hb_out, float* __restrict__ hbrev_out) {
    __shared__ float hb_lds[16][DD];
    const int blk   = blockIdx.x;
    const int b     = blk >> 2;
    const int group = blk & 3;
    const int tid   = threadIdx.x;
    const int wave  = tid >> 6;
    const int lane  = tid & 63;
    const int d0    = lane << 2;

#pragma unroll
    for (int q = 0; q < 4; ++q) {
        const int el = wave * 4 + q;           // local bond 0..15
        const int be = b * EE + group * 16 + el;

        // --- categorical part: sum of 3 table rows, then LN ---
        const int* fc = bfc + be * 3;
        const int i0 = fc[0] + 1;
        const int i1 = fc[1] + 12;
        const int i2 = fc[2] + 23;
        float4 r0 = *(const float4*)(table_bc + i0 * DD + d0);
        float4 r1 = *(const float4*)(table_bc + i1 * DD + d0);
        float4 r2 = *(const float4*)(table_bc + i2 * DD + d0);
        float x0 = r0.x + r1.x + r2.x;
        float x1 = r0.y + r1.y + r2.y;
        float x2 = r0.z + r1.z + r2.z;
        float x3 = r0.w + r1.w + r2.w;
        ln4(x0, x1, x2, x3, g_bc, be_bc, d0);

        // --- float part: [4] @ W_bf[4,256] + b_bf, then LN ---
        float4 fr = *(const float4*)(bff + be * 4);
        float4 w0 = *(const float4*)(W_bf + 0 * DD + d0);
        float4 w1 = *(const float4*)(W_bf + 1 * DD + d0);
        float4 w2 = *(const float4*)(W_bf + 2 * DD + d0);
        float4 w3 = *(const float4*)(W_bf + 3 * DD + d0);
        float4 bb = *(const float4*)(b_bf + d0);
        float y0 = bb.x + fr.x * w0.x + fr.y * w1.x + fr.z * w2.x + fr.w * w3.x;
        float y1 = bb.y + fr.x * w0.y + fr.y * w1.y + fr.z * w2.y + fr.w * w3.y;
        float y2 = bb.z + fr.x * w0.z + fr.y * w1.z + fr.z * w2.z + fr.w * w3.z;
        float y3 = bb.w + fr.x * w0.w + fr.y * w1.w + fr.z * w2.w + fr.w * w3.w;
        ln4(y0, y1, y2, y3, g_bf, be_bf, d0);

        const float m = bmask[be];
        const float h0 = (x0 + y0) * m;
        const float h1 = (x1 + y1) * m;
        const float h2 = (x2 + y2) * m;
        const float h3 = (x3 + y3) * m;

        *(float4*)&hb_lds[el][d0] = make_float4(h0, h1, h2, h3);
        *(float4*)(hb_out + (size_t)be * DD + d0) = make_float4(h0, h1, h2, h3);
    }
    __syncthreads();

    // --- phase 2: hbrev[e][d] = b_rev[d] + sum_k hb[e][k] * W_rev[k][d] ---
    const int d = tid;  // output column 0..255
    const float brv = b_rev[d];
    float acc[16];
#pragma unroll
    for (int e = 0; e < 16; ++e) acc[e] = brv;
    for (int k = 0; k < DD; k += 4) {
        const float w0 = W_rev[(k + 0) * DD + d];
        const float w1 = W_rev[(k + 1) * DD + d];
        const float w2 = W_rev[(k + 2) * DD + d];
        const float w3 = W_rev[(k + 3) * DD + d];
#pragma unroll
        for (int e = 0; e < 16; ++e) {
            float4 h = *(const float4*)&hb_lds[e][k];  // broadcast read, conflict-free
            acc[e] += h.x * w0 + h.y * w1 + h.z * w2 + h.w * w3;
        }
    }
    const int be0 = b * EE + group * 16;
#pragma unroll
    for (int e = 0; e < 16; ++e) {
        hbrev_out[(size_t)(be0 + e) * DD + d] = acc[e];
    }
}

// ---------------------------------------------------------------------------
// Kernel 3: one wave per output cell (b,i,j); lane owns d = 4*lane..4*lane+3.
// grid = B*M*M/4 blocks of 256 threads (4 independent waves/block, no barriers).
// ---------------------------------------------------------------------------
__global__ __launch_bounds__(256) void k_cells(
    const int* __restrict__ sfc, const float* __restrict__ sff,
    const float* __restrict__ table_sc,
    const float* __restrict__ g_sc, const float* __restrict__ be_sc,
    const float* __restrict__ W_sf, const float* __restrict__ b_sf,
    const float* __restrict__ g_sf, const float* __restrict__ be_sf,
    const float* __restrict__ vee,
    const u64* __restrict__ maskA, const u64* __restrict__ maskB,
    const float* __restrict__ hb, const float* __restrict__ hbrev,
    float* __restrict__ out) {
    const int wave = threadIdx.x >> 6;
    const int lane = threadIdx.x & 63;
    const int cell = blockIdx.x * 4 + wave;       // < B*M*M = 307328 exactly
    const int b = cell / (MM * MM);
    const int r = cell - b * (MM * MM);
    const int i = r / MM;
    const int j = r - i * MM;
    const int d0 = lane << 2;
    float* op = out + (size_t)cell * DD + d0;

    if (i == 0 || j == 0) {  // virtual edge row/col
        *(float4*)op = *(const float4*)(vee + d0);
        return;
    }

    const int ii = i - 1, jj = j - 1;
    const int cidx = (b * NN + ii) * NN + jj;

    // --- categorical: sum of 4 table rows, LN ---
    const int4 fc = *(const int4*)(sfc + cidx * 4);
    float4 r0 = *(const float4*)(table_sc + (fc.x + 1)  * DD + d0);
    float4 r1 = *(const float4*)(table_sc + (fc.y + 12) * DD + d0);
    float4 r2 = *(const float4*)(table_sc + (fc.z + 23) * DD + d0);
    float4 r3 = *(const float4*)(table_sc + (fc.w + 34) * DD + d0);
    float x0 = r0.x + r1.x + r2.x + r3.x;
    float x1 = r0.y + r1.y + r2.y + r3.y;
    float x2 = r0.z + r1.z + r2.z + r3.z;
    float x3 = r0.w + r1.w + r2.w + r3.w;
    ln4(x0, x1, x2, x3, g_sc, be_sc, d0);

    // --- float: [8] @ W_sf[8,256] + b_sf, LN ---
    const float* fp = sff + (size_t)cidx * 8;
    float4 fa = *(const float4*)fp;
    float4 fb = *(const float4*)(fp + 4);
    float f[8] = {fa.x, fa.y, fa.z, fa.w, fb.x, fb.y, fb.z, fb.w};
    float4 bbv = *(const float4*)(b_sf + d0);
    float y0 = bbv.x, y1 = bbv.y, y2 = bbv.z, y3 = bbv.w;
#pragma unroll
    for (int ff = 0; ff < 8; ++ff) {
        float4 wr = *(const float4*)(W_sf + ff * DD + d0);
        y0 += f[ff] * wr.x;
        y1 += f[ff] * wr.y;
        y2 += f[ff] * wr.z;
        y3 += f[ff] * wr.w;
    }
    ln4(y0, y1, y2, y3, g_sf, be_sf, d0);

    float h0 = x0 + y0, h1 = x1 + y1, h2 = x2 + y2, h3 = x3 + y3;

    // --- sparse bond contributions via bitmask gather ---
    const u64 mAi = maskA[b * MM + i];
    const u64 mBj = maskB[b * MM + j];
    const u64 mBi = maskB[b * MM + i];
    const u64 mAj = maskA[b * MM + j];
    u64 fwd = mAi & mBj;  // bonds (i,j): add hb
    u64 rev = mBi & mAj;  // bonds (j,i): add hbrev
    while (fwd) {
        const int e = __builtin_ctzll(fwd); fwd &= fwd - 1;
        float4 hv = *(const float4*)(hb + (size_t)(b * EE + e) * DD + d0);
        h0 += hv.x; h1 += hv.y; h2 += hv.z; h3 += hv.w;
    }
    while (rev) {
        const int e = __builtin_ctzll(rev); rev &= rev - 1;
        float4 hv = *(const float4*)(hbrev + (size_t)(b * EE + e) * DD + d0);
        h0 += hv.x; h1 += hv.y; h2 += hv.z; h3 += hv.w;
    }

    *(float4*)op = make_float4(h0, h1, h2, h3);
}

// ---------------------------------------------------------------------------
extern "C" void kernel_launch(void* const* d_in, const int* in_sizes, int n_in,
                              void* d_out, int out_size, void* d_ws, size_t ws_size,
                              hipStream_t stream) {
    const int*   bond_index = (const int*)d_in[0];
    const int*   bfc        = (const int*)d_in[1];
    const float* bff        = (const float*)d_in[2];
    const float* bmask      = (const float*)d_in[3];
    const int*   sfc        = (const int*)d_in[4];
    const float* sff        = (const float*)d_in[5];
    const float* table_bc   = (const float*)d_in[6];
    const float* g_bc       = (const float*)d_in[7];
    const float* be_bc      = (const float*)d_in[8];
    const float* W_bf       = (const float*)d_in[9];
    const float* b_bf       = (const float*)d_in[10];
    const float* g_bf       = (const float*)d_in[11];
    const float* be_bf      = (const float*)d_in[12];
    const float* table_sc   = (const float*)d_in[13];
    const float* g_sc       = (const float*)d_in[14];
    const float* be_sc      = (const float*)d_in[15];
    const float* W_sf       = (const float*)d_in[16];
    const float* b_sf       = (const float*)d_in[17];
    const float* g_sf       = (const float*)d_in[18];
    const float* be_sf      = (const float*)d_in[19];
    const float* vee        = (const float*)d_in[20];
    const float* W_rev      = (const float*)d_in[21];
    const float* b_rev      = (const float*)d_in[22];

    float* out = (float*)d_out;

    // ws layout: hb[8192*256] f32 | hbrev[8192*256] f32 | maskA[128*49] u64 | maskB
    float* hb    = (float*)d_ws;
    float* hbrev = hb + (size_t)BB * EE * DD;
    u64*   maskA = (u64*)(hbrev + (size_t)BB * EE * DD);
    u64*   maskB = maskA + BB * MM;

    k_masks<<<BB, 64, 0, stream>>>(bond_index, maskA, maskB);
    k_bonds<<<BB * 4, 256, 0, stream>>>(bfc, bff, bmask, table_bc, g_bc, be_bc,
                                        W_bf, b_bf, g_bf, be_bf, W_rev, b_rev,
                                        hb, hbrev);
    k_cells<<<(BB * MM * MM) / 4, 256, 0, stream>>>(sfc, sff, table_sc, g_sc, be_sc,
                                                    W_sf, b_sf, g_sf, be_sf, vee,
                                                    maskA, maskB, hb, hbrev, out);
}

// Round 5
// 465.903 us; speedup vs baseline: 1.2429x; 1.2429x over previous
//
#include <hip/hip_runtime.h>

// Shapes (fixed by the reference):
//   B=128, N=48, M=49, E=64, D=256
//   NUMS_BC=[11,11,11]  -> idx offsets {1,12,23}
//   NUMS_SC=[11,11,11,11]-> idx offsets {1,12,23,34}
// All float inputs/outputs are float32; int inputs are int32.
//
// Strategy: LayerNorm statistics for the dense [B,N,N] block are computed
// WITHOUT any cross-lane reduction, via precomputed row means + centered Gram
// matrices:  y = sum_k c_k V_k  =>  mu = sum c_k m_k, var = c^T Ghat c.
// A 1-thread-per-cell prep kernel produces {mu_c, rs_c, mu_f, rs_f} per cell;
// the main cell kernel is then pure streaming FMA + coalesced float4 store.

#define DD 256
#define BB 128
#define NN 48
#define MM 49
#define EE 64
#define NSC 44   // table_sc rows
#define NSF 9    // [b_sf, W_sf rows 0..7]

typedef unsigned long long u64;

__device__ __forceinline__ float wredsum(float s) {
#pragma unroll
    for (int off = 32; off > 0; off >>= 1) s += __shfl_xor(s, off, 64);
    return s;
}

// Wave-level fused (sum, sumsq) reduction across 64 lanes (bond kernel only).
__device__ __forceinline__ void wred2(float& s, float& q) {
#pragma unroll
    for (int off = 32; off > 0; off >>= 1) {
        s += __shfl_xor(s, off, 64);
        q += __shfl_xor(q, off, 64);
    }
}

__device__ __forceinline__ void ln4(float& x0, float& x1, float& x2, float& x3,
                                    const float* __restrict__ g,
                                    const float* __restrict__ bb, int d0) {
    float s = x0 + x1 + x2 + x3;
    float q = x0 * x0 + x1 * x1 + x2 * x2 + x3 * x3;
    wred2(s, q);
    float mu  = s * (1.0f / 256.0f);
    float var = q * (1.0f / 256.0f) - mu * mu;
    float rs  = rsqrtf(var + 1e-5f);
    float4 gv = *(const float4*)(g + d0);
    float4 bv = *(const float4*)(bb + d0);
    x0 = (x0 - mu) * rs * gv.x + bv.x;
    x1 = (x1 - mu) * rs * gv.y + bv.y;
    x2 = (x2 - mu) * rs * gv.z + bv.z;
    x3 = (x3 - mu) * rs * gv.w + bv.w;
}

// ---------------------------------------------------------------------------
// Kernel 1: per-batch bond bitmasks. grid=B, block=64 (one wave).
// ---------------------------------------------------------------------------
__global__ __launch_bounds__(64) void k_masks(const int* __restrict__ bond_index,
                                              u64* __restrict__ maskA,
                                              u64* __restrict__ maskB) {
    const int b = blockIdx.x;
    const int e = threadIdx.x;  // 0..63
    const int bi0 = bond_index[b * 2 * EE + e];
    const int bi1 = bond_index[b * 2 * EE + EE + e];
    for (int i = 0; i < NN; ++i) {
        u64 mA = __ballot(bi0 == i);
        u64 mB = __ballot(bi1 == i);
        if (e == 0) {
            maskA[b * MM + i + 1] = mA;
            maskB[b * MM + i + 1] = mB;
        }
    }
}

// ---------------------------------------------------------------------------
// Kernel P1: row means. wave w: rows 0..43 = table_sc, 44 = b_sf, 45..52 = W_sf.
// ---------------------------------------------------------------------------
__global__ __launch_bounds__(256) void k_prep_means(const float* __restrict__ table_sc,
                                                    const float* __restrict__ W_sf,
                                                    const float* __restrict__ b_sf,
                                                    float* __restrict__ m_sc,
                                                    float* __restrict__ m_sf) {
    const int w = (blockIdx.x * 256 + threadIdx.x) >> 6;
    const int lane = threadIdx.x & 63;
    if (w >= NSC + NSF) return;
    const float* src = (w < NSC) ? table_sc + w * DD
                     : (w == NSC) ? b_sf
                                  : W_sf + (w - NSC - 1) * DD;
    float4 v = *(const float4*)(src + lane * 4);
    float s = wredsum(v.x + v.y + v.z + v.w);
    if (lane == 0) {
        if (w < NSC) m_sc[w] = s * (1.0f / 256.0f);
        else         m_sf[w - NSC] = s * (1.0f / 256.0f);
    }
}

// ---------------------------------------------------------------------------
// Kernel P2: centered Gram matrices. One wave per (a,c) pair.
// waves [0, 44*44) -> G_sc ; [1936, 1936+81) -> G_sf.
// ---------------------------------------------------------------------------
__global__ __launch_bounds__(256) void k_prep_gram(const float* __restrict__ table_sc,
                                                   const float* __restrict__ W_sf,
                                                   const float* __restrict__ b_sf,
                                                   const float* __restrict__ m_sc,
                                                   const float* __restrict__ m_sf,
                                                   float* __restrict__ G_sc,
                                                   float* __restrict__ G_sf) {
    const int w = (blockIdx.x * 256 + threadIdx.x) >> 6;
    const int lane = threadIdx.x & 63;
    if (w < NSC * NSC) {
        const int a = w / NSC, c = w - a * NSC;
        float4 va = *(const float4*)(table_sc + a * DD + lane * 4);
        float4 vc = *(const float4*)(table_sc + c * DD + lane * 4);
        float s = wredsum(va.x * vc.x + va.y * vc.y + va.z * vc.z + va.w * vc.w);
        if (lane == 0) G_sc[w] = s * (1.0f / 256.0f) - m_sc[a] * m_sc[c];
    } else if (w < NSC * NSC + NSF * NSF) {
        const int p = w - NSC * NSC;
        const int a = p / NSF, c = p - a * NSF;
        const float* ra = (a == 0) ? b_sf : W_sf + (a - 1) * DD;
        const float* rc = (c == 0) ? b_sf : W_sf + (c - 1) * DD;
        float4 va = *(const float4*)(ra + lane * 4);
        float4 vc = *(const float4*)(rc + lane * 4);
        float s = wredsum(va.x * vc.x + va.y * vc.y + va.z * vc.z + va.w * vc.w);
        if (lane == 0) G_sf[p] = s * (1.0f / 256.0f) - m_sf[a] * m_sf[c];
    }
}

// ---------------------------------------------------------------------------
// Kernel P3: per-cell LN params {mu_c, rs_c, mu_f, rs_f}. 1 thread per cell.
// ---------------------------------------------------------------------------
__global__ __launch_bounds__(256) void k_prep_cells(const int* __restrict__ sfc,
                                                    const float* __restrict__ sff,
                                                    const float* __restrict__ m_sc,
                                                    const float* __restrict__ G_sc,
                                                    const float* __restrict__ m_sf,
                                                    const float* __restrict__ G_sf,
                                                    float4* __restrict__ cellp) {
    const int c = blockIdx.x * 256 + threadIdx.x;  // < B*N*N = 294912 exactly
    const int4 fc = *(const int4*)(sfc + (size_t)c * 4);
    int r[4] = {fc.x + 1, fc.y + 12, fc.z + 23, fc.w + 34};
    float mu_c = m_sc[r[0]] + m_sc[r[1]] + m_sc[r[2]] + m_sc[r[3]];
    float var_c = 0.f;
#pragma unroll
    for (int a = 0; a < 4; ++a)
#pragma unroll
        for (int d = 0; d < 4; ++d) var_c += G_sc[r[a] * NSC + r[d]];

    float f[NSF];
    f[0] = 1.f;
    float4 fa = *(const float4*)(sff + (size_t)c * 8);
    float4 fb = *(const float4*)(sff + (size_t)c * 8 + 4);
    f[1] = fa.x; f[2] = fa.y; f[3] = fa.z; f[4] = fa.w;
    f[5] = fb.x; f[6] = fb.y; f[7] = fb.z; f[8] = fb.w;
    float mu_f = 0.f, var_f = 0.f;
#pragma unroll
    for (int k = 0; k < NSF; ++k) {
        mu_f += f[k] * m_sf[k];
        float t = 0.f;
#pragma unroll
        for (int l = 0; l < NSF; ++l) t += f[l] * G_sf[k * NSF + l];
        var_f += f[k] * t;
    }
    cellp[c] = make_float4(mu_c, rsqrtf(var_c + 1e-5f), mu_f, rsqrtf(var_f + 1e-5f));
}

// ---------------------------------------------------------------------------
// Kernel 2: bond embeddings hb (f32, ws) and hbrev = hb @ W_rev + b_rev.
// ---------------------------------------------------------------------------
__global__ __launch_bounds__(256) void k_bonds(
    const int* __restrict__ bfc, const float* __restrict__ bff,
    const float* __restrict__ bmask,
    const float* __restrict__ table_bc,
    const float* __restrict__ g_bc, const float* __restrict__ be_bc,
    const float* __restrict__ W_bf, const float* __restrict__ b_bf,
    const float* __restrict__ g_bf, const float* __restrict__ be_bf,
    const float* __restrict__ W_rev, const float* __restrict__ b_rev,
    float* __restrict__ hb_out, float* __restrict__ hbrev_out) {
    __shared__ float hb_lds[16][DD];
    const int blk   = blockIdx.x;
    const int b     = blk >> 2;
    const int group = blk & 3;
    const int tid   = threadIdx.x;
    const int wave  = tid >> 6;
    const int lane  = tid & 63;
    const int d0    = lane << 2;

#pragma unroll
    for (int q = 0; q < 4; ++q) {
        const int el = wave * 4 + q;           // local bond 0..15
        const int be = b * EE + group * 16 + el;

        const int* fc = bfc + be * 3;
        const int i0 = fc[0] + 1;
        const int i1 = fc[1] + 12;
        const int i2 = fc[2] + 23;
        float4 r0 = *(const float4*)(table_bc + i0 * DD + d0);
        float4 r1 = *(const float4*)(table_bc + i1 * DD + d0);
        float4 r2 = *(const float4*)(table_bc + i2 * DD + d0);
        float x0 = r0.x + r1.x + r2.x;
        float x1 = r0.y + r1.y + r2.y;
        float x2 = r0.z + r1.z + r2.z;
        float x3 = r0.w + r1.w + r2.w;
        ln4(x0, x1, x2, x3, g_bc, be_bc, d0);

        float4 fr = *(const float4*)(bff + be * 4);
        float4 w0 = *(const float4*)(W_bf + 0 * DD + d0);
        float4 w1 = *(const float4*)(W_bf + 1 * DD + d0);
        float4 w2 = *(const float4*)(W_bf + 2 * DD + d0);
        float4 w3 = *(const float4*)(W_bf + 3 * DD + d0);
        float4 bb = *(const float4*)(b_bf + d0);
        float y0 = bb.x + fr.x * w0.x + fr.y * w1.x + fr.z * w2.x + fr.w * w3.x;
        float y1 = bb.y + fr.x * w0.y + fr.y * w1.y + fr.z * w2.y + fr.w * w3.y;
        float y2 = bb.z + fr.x * w0.z + fr.y * w1.z + fr.z * w2.z + fr.w * w3.z;
        float y3 = bb.w + fr.x * w0.w + fr.y * w1.w + fr.z * w2.w + fr.w * w3.w;
        ln4(y0, y1, y2, y3, g_bf, be_bf, d0);

        const float m = bmask[be];
        const float h0 = (x0 + y0) * m;
        const float h1 = (x1 + y1) * m;
        const float h2 = (x2 + y2) * m;
        const float h3 = (x3 + y3) * m;

        *(float4*)&hb_lds[el][d0] = make_float4(h0, h1, h2, h3);
        *(float4*)(hb_out + (size_t)be * DD + d0) = make_float4(h0, h1, h2, h3);
    }
    __syncthreads();

    const int d = tid;  // output column 0..255
    const float brv = b_rev[d];
    float acc[16];
#pragma unroll
    for (int e = 0; e < 16; ++e) acc[e] = brv;
    for (int k = 0; k < DD; k += 4) {
        const float w0 = W_rev[(k + 0) * DD + d];
        const float w1 = W_rev[(k + 1) * DD + d];
        const float w2 = W_rev[(k + 2) * DD + d];
        const float w3 = W_rev[(k + 3) * DD + d];
#pragma unroll
        for (int e = 0; e < 16; ++e) {
            float4 h = *(const float4*)&hb_lds[e][k];
            acc[e] += h.x * w0 + h.y * w1 + h.z * w2 + h.w * w3;
        }
    }
    const int be0 = b * EE + group * 16;
#pragma unroll
    for (int e = 0; e < 16; ++e) {
        hbrev_out[(size_t)(be0 + e) * DD + d] = acc[e];
    }
}

// ---------------------------------------------------------------------------
// Kernel 3: one wave per 7 consecutive j-cells of row (b,i). No cross-lane
// ops; per-cell metadata via scalar loads (readfirstlane'd wave id).
// waves = B*M*7 = 43904 ; grid = 10976 blocks x 256.
// ---------------------------------------------------------------------------
__global__ __launch_bounds__(256) void k_cells(
    const int* __restrict__ sfc, const float* __restrict__ sff,
    const float* __restrict__ table_sc,
    const float* __restrict__ g_sc, const float* __restrict__ be_sc,
    const float* __restrict__ W_sf, const float* __restrict__ b_sf,
    const float* __restrict__ g_sf, const float* __restrict__ be_sf,
    const float* __restrict__ vee,
    const u64* __restrict__ maskA, const u64* __restrict__ maskB,
    const float* __restrict__ hb, const float* __restrict__ hbrev,
    const float4* __restrict__ cellp,
    float* __restrict__ out) {
    const int lane = threadIdx.x & 63;
    const int d0 = lane << 2;
    const int wid = __builtin_amdgcn_readfirstlane(blockIdx.x * 4 + (threadIdx.x >> 6));
    const int b  = wid / (MM * 7);
    const int rr = wid - b * (MM * 7);
    const int i  = rr / 7;          // 0..48
    const int jc = rr - i * 7;      // 0..6
    const int j0 = jc * 7;          // 0,7,...,42

    const float4 veev = *(const float4*)(vee + d0);
    float* orow = out + (((size_t)b * MM + i) * MM + j0) * DD + d0;

    if (i == 0) {
#pragma unroll
        for (int jj = 0; jj < 7; ++jj) *(float4*)(orow + jj * DD) = veev;
        return;
    }

    // hoisted per-wave constants
    const float4 gsc  = *(const float4*)(g_sc + d0);
    const float4 bsc  = *(const float4*)(be_sc + d0);
    const float4 gsf  = *(const float4*)(g_sf + d0);
    const float4 bsf2 = *(const float4*)(be_sf + d0);
    const float4 bsf  = *(const float4*)(b_sf + d0);
    float4 w[8];
#pragma unroll
    for (int k = 0; k < 8; ++k) w[k] = *(const float4*)(W_sf + k * DD + d0);

    const u64 mAi = maskA[b * MM + i];
    const u64 mBi = maskB[b * MM + i];
    const float* hbB = hb    + ((size_t)b * EE) * DD + d0;
    const float* hrB = hbrev + ((size_t)b * EE) * DD + d0;
    const int rowbase = (b * NN + (i - 1)) * NN - 1;  // cidx = rowbase + j

    for (int jj = 0; jj < 7; ++jj) {
        const int j = j0 + jj;
        float* op = orow + jj * DD;
        if (j == 0) { *(float4*)op = veev; continue; }

        const int cidx = rowbase + j;
        const int4 fc  = *(const int4*)(sfc + (size_t)cidx * 4);
        const float4 p = cellp[cidx];  // {mu_c, rs_c, mu_f, rs_f}
        const float4 t0 = *(const float4*)(table_sc + (fc.x + 1)  * DD + d0);
        const float4 t1 = *(const float4*)(table_sc + (fc.y + 12) * DD + d0);
        const float4 t2 = *(const float4*)(table_sc + (fc.z + 23) * DD + d0);
        const float4 t3 = *(const float4*)(table_sc + (fc.w + 34) * DD + d0);
        const float4 fa  = *(const float4*)(sff + (size_t)cidx * 8);
        const float4 fbv = *(const float4*)(sff + (size_t)cidx * 8 + 4);

        float x0 = t0.x + t1.x + t2.x + t3.x;
        float x1 = t0.y + t1.y + t2.y + t3.y;
        float x2 = t0.z + t1.z + t2.z + t3.z;
        float x3 = t0.w + t1.w + t2.w + t3.w;
        x0 = (x0 - p.x) * p.y * gsc.x + bsc.x;
        x1 = (x1 - p.x) * p.y * gsc.y + bsc.y;
        x2 = (x2 - p.x) * p.y * gsc.z + bsc.z;
        x3 = (x3 - p.x) * p.y * gsc.w + bsc.w;

        float y0 = bsf.x + fa.x * w[0].x + fa.y * w[1].x + fa.z * w[2].x + fa.w * w[3].x
                         + fbv.x * w[4].x + fbv.y * w[5].x + fbv.z * w[6].x + fbv.w * w[7].x;
        float y1 = bsf.y + fa.x * w[0].y + fa.y * w[1].y + fa.z * w[2].y + fa.w * w[3].y
                         + fbv.x * w[4].y + fbv.y * w[5].y + fbv.z * w[6].y + fbv.w * w[7].y;
        float y2 = bsf.z + fa.x * w[0].z + fa.y * w[1].z + fa.z * w[2].z + fa.w * w[3].z
                         + fbv.x * w[4].z + fbv.y * w[5].z + fbv.z * w[6].z + fbv.w * w[7].z;
        float y3 = bsf.w + fa.x * w[0].w + fa.y * w[1].w + fa.z * w[2].w + fa.w * w[3].w
                         + fbv.x * w[4].w + fbv.y * w[5].w + fbv.z * w[6].w + fbv.w * w[7].w;
        y0 = (y0 - p.z) * p.w * gsf.x + bsf2.x;
        y1 = (y1 - p.z) * p.w * gsf.y + bsf2.y;
        y2 = (y2 - p.z) * p.w * gsf.z + bsf2.z;
        y3 = (y3 - p.z) * p.w * gsf.w + bsf2.w;

        float h0 = x0 + y0, h1 = x1 + y1, h2 = x2 + y2, h3 = x3 + y3;

        const u64 mAj = maskA[b * MM + j];
        const u64 mBj = maskB[b * MM + j];
        u64 fwd = mAi & mBj;  // bonds (i,j): add hb
        u64 rev = mBi & mAj;  // bonds (j,i): add hbrev
        while (fwd) {
            const int e = __builtin_ctzll(fwd); fwd &= fwd - 1;
            float4 hv = *(const float4*)(hbB + (size_t)e * DD);
            h0 += hv.x; h1 += hv.y; h2 += hv.z; h3 += hv.w;
        }
        while (rev) {
            const int e = __builtin_ctzll(rev); rev &= rev - 1;
            float4 hv = *(const float4*)(hrB + (size_t)e * DD);
            h0 += hv.x; h1 += hv.y; h2 += hv.z; h3 += hv.w;
        }

        *(float4*)op = make_float4(h0, h1, h2, h3);
    }
}

// ---------------------------------------------------------------------------
extern "C" void kernel_launch(void* const* d_in, const int* in_sizes, int n_in,
                              void* d_out, int out_size, void* d_ws, size_t ws_size,
                              hipStream_t stream) {
    const int*   bond_index = (const int*)d_in[0];
    const int*   bfc        = (const int*)d_in[1];
    const float* bff        = (const float*)d_in[2];
    const float* bmask      = (const float*)d_in[3];
    const int*   sfc        = (const int*)d_in[4];
    const float* sff        = (const float*)d_in[5];
    const float* table_bc   = (const float*)d_in[6];
    const float* g_bc       = (const float*)d_in[7];
    const float* be_bc      = (const float*)d_in[8];
    const float* W_bf       = (const float*)d_in[9];
    const float* b_bf       = (const float*)d_in[10];
    const float* g_bf       = (const float*)d_in[11];
    const float* be_bf      = (const float*)d_in[12];
    const float* table_sc   = (const float*)d_in[13];
    const float* g_sc       = (const float*)d_in[14];
    const float* be_sc      = (const float*)d_in[15];
    const float* W_sf       = (const float*)d_in[16];
    const float* b_sf       = (const float*)d_in[17];
    const float* g_sf       = (const float*)d_in[18];
    const float* be_sf      = (const float*)d_in[19];
    const float* vee        = (const float*)d_in[20];
    const float* W_rev      = (const float*)d_in[21];
    const float* b_rev      = (const float*)d_in[22];

    float* out = (float*)d_out;

    // ws layout (floats unless noted):
    float* hb    = (float*)d_ws;                                  // 2,097,152
    float* hbrev = hb + (size_t)BB * EE * DD;                     // 2,097,152
    u64*   maskA = (u64*)(hbrev + (size_t)BB * EE * DD);          // 6272 u64
    u64*   maskB = maskA + BB * MM;                               // 6272 u64
    float* m_sc  = (float*)(maskB + BB * MM);                     // 44
    float* G_sc  = m_sc + NSC;                                    // 1936
    float* m_sf  = G_sc + NSC * NSC;                              // 9
    float* G_sf  = m_sf + NSF;                                    // 81
    float* endp  = G_sf + NSF * NSF;
    float4* cellp = (float4*)(((unsigned long long)endp + 15ull) & ~15ull);  // 294912 float4

    k_masks<<<BB, 64, 0, stream>>>(bond_index, maskA, maskB);
    k_prep_means<<<(NSC + NSF + 3) / 4, 256, 0, stream>>>(table_sc, W_sf, b_sf, m_sc, m_sf);
    k_prep_gram<<<(NSC * NSC + NSF * NSF + 3) / 4, 256, 0, stream>>>(
        table_sc, W_sf, b_sf, m_sc, m_sf, G_sc, G_sf);
    k_prep_cells<<<(BB * NN * NN) / 256, 256, 0, stream>>>(sfc, sff, m_sc, G_sc, m_sf, G_sf, cellp);
    k_bonds<<<BB * 4, 256, 0, stream>>>(bfc, bff, bmask, table_bc, g_bc, be_bc,
                                        W_bf, b_bf, g_bf, be_bf, W_rev, b_rev,
                                        hb, hbrev);
    k_cells<<<(BB * MM * 7) / 4, 256, 0, stream>>>(sfc, sff, table_sc, g_sc, be_sc,
                                                   W_sf, b_sf, g_sf, be_sf, vee,
                                                   maskA, maskB, hb, hbrev, cellp, out);
}